// Round 7
// baseline (113.588 us; speedup 1.0000x reference)
//
#include <hip/hip_runtime.h>
#include <hip/hip_bf16.h>

// MMD loss via bf16 hi/lo-split MFMA Gram pass — plane-fused K-chunks,
// counted-vmcnt depth-2 pipeline (T4) with raw s_barrier (no compiler drain).
//   dot ~= hi.hi + hi.lo + lo.hi ; per K-chunk stage {A_hi,A_lo,B_hi,B_lo}
//   d2 = sq_i + sq_j - 2 dot;  kernels = u+u^2+u^4+u^8+u^16, u=2^(negc*d2)
// 128^2 tile, 4 waves (2x2 of 64x64), mfma_f32_32x32x16_bf16, BK=32,
// dbuf 64KB. Schedule per chunk:
//   vmcnt(8) [chunk kt landed; kt+1's 8 loads stay in flight] ; s_barrier
//   ds_read+MFMA ; lgkmcnt(0) ; s_barrier ; STAGE(kt+2) into freed buffer.

#define N_TOTAL 8192
#define B_HALF 4096
#define D_DIM 256
#define TILE 128
#define NTILE 64          // 8192/128
#define NTRI 2080         // 64*65/2
#define BK 32
#define NCHUNK 8          // 256/32

typedef float f32x16 __attribute__((ext_vector_type(16)));
typedef short s16x8 __attribute__((ext_vector_type(8)));

__device__ __forceinline__ const float* row_base(const float* src, const float* tgt, int r) {
    return (r < B_HALF) ? src + (size_t)r * D_DIM : tgt + (size_t)(r - B_HALF) * D_DIM;
}

// fused split (hi/lo bf16) + row sq. one wave per row, 4 rows/block.
__global__ __launch_bounds__(256) void prep_kernel(const float* __restrict__ src,
                                                   const float* __restrict__ tgt,
                                                   ushort* __restrict__ hi,
                                                   ushort* __restrict__ lo,
                                                   float* __restrict__ sq) {
    int w = threadIdx.x >> 6, lane = threadIdx.x & 63;
    int row = blockIdx.x * 4 + w;
    const float* rp = row_base(src, tgt, row);
    float4 v = ((const float4*)rp)[lane];
    float f[4] = {v.x, v.y, v.z, v.w};
    ushort h[4], l[4];
    #pragma unroll
    for (int e = 0; e < 4; ++e) {
        __hip_bfloat16 hb = __float2bfloat16(f[e]);
        float hf = __bfloat162float(hb);
        __hip_bfloat16 lb = __float2bfloat16(f[e] - hf);
        h[e] = *(ushort*)&hb;
        l[e] = *(ushort*)&lb;
    }
    size_t base = (size_t)row * D_DIM + lane * 4;
    *(ushort4*)(hi + base) = *(ushort4*)h;
    *(ushort4*)(lo + base) = *(ushort4*)l;
    float s = f[0]*f[0] + f[1]*f[1] + f[2]*f[2] + f[3]*f[3];
    #pragma unroll
    for (int off = 32; off; off >>= 1) s += __shfl_down(s, off, 64);
    if (lane == 0) sq[row] = s;
}

// per-block partial column sums (no atomics)
__global__ __launch_bounds__(256) void colpart_kernel(const float* __restrict__ src,
                                                      const float* __restrict__ tgt,
                                                      float* __restrict__ colpart) {
    int t  = threadIdx.x;
    int r0 = blockIdx.x * 128;
    float s = 0.f;
    for (int r = r0; r < r0 + 128; ++r)
        s += row_base(src, tgt, r)[t];
    colpart[blockIdx.x * D_DIM + t] = s;
}

__global__ __launch_bounds__(256) void bw_kernel(const float* __restrict__ sq,
                                                 const float* __restrict__ colpart,
                                                 float* __restrict__ negc,
                                                 double* __restrict__ accum) {
    __shared__ double red[256];
    int t = threadIdx.x;
    double s = 0.0;
    for (int i = t; i < N_TOTAL; i += 256) s += (double)sq[i];
    red[t] = s;
    __syncthreads();
    for (int off = 128; off; off >>= 1) {
        if (t < off) red[t] += red[t + off];
        __syncthreads();
    }
    double sumsq = red[0];
    __syncthreads();
    float c = 0.f;
    for (int k = 0; k < 64; ++k) c += colpart[k * D_DIM + t];
    red[t] = (double)c * (double)c;
    __syncthreads();
    for (int off = 128; off; off >>= 1) {
        if (t < off) red[t] += red[t + off];
        __syncthreads();
    }
    if (t == 0) {
        double S1 = 2.0 * (double)N_TOTAL * sumsq - 2.0 * red[0];
        double nn = (double)N_TOTAL * (double)N_TOTAL - (double)N_TOTAL;
        double bw = S1 / nn / 4.0;    // KERNEL_MUL^(KERNEL_NUM//2) = 4
        negc[0] = (float)(-1.4426950408889634 / (16.0 * bw));
        accum[0] = 0.0;
    }
}

__device__ __forceinline__ void gload_lds16(const void* g, void* l) {
    __builtin_amdgcn_global_load_lds((const __attribute__((address_space(1))) unsigned int*)g,
                                     (__attribute__((address_space(3))) unsigned int*)l,
                                     16, 0, 0);
}

__global__ __launch_bounds__(256, 2) void mmd_mfma(const ushort* __restrict__ hi,
                                                   const ushort* __restrict__ lo,
                                                   const float* __restrict__ sq,
                                                   const float* __restrict__ negc,
                                                   double* __restrict__ accum) {
    // [buf][tile: 0=A_hi 1=A_lo 2=B_hi 3=B_lo][128 rows x 32 k]  = 64 KB
    __shared__ ushort lds[2][4][TILE * BK];
    __shared__ float wsum[4];

    // T1: XCD swizzle (2080 % 8 == 0 -> bijective), then triangle decode
    int b  = blockIdx.x;
    int bs = (b & 7) * (NTRI / 8) + (b >> 3);
    int it = 0, cum = 0;
    while (cum + (NTILE - it) <= bs) { cum += NTILE - it; ++it; }
    int jt = it + (bs - cum);

    int tid = threadIdx.x, lane = tid & 63, wid = tid >> 6;
    int wrow = wid >> 1, wcol = wid & 1;      // 2x2 wave grid; per-wave 64x64
    int rowA = it * TILE, rowB = jt * TILE;
    int c32 = lane & 31, khalf = lane >> 5;

    const ushort* srcs[4] = { hi + (size_t)rowA * D_DIM, lo + (size_t)rowA * D_DIM,
                              hi + (size_t)rowB * D_DIM, lo + (size_t)rowB * D_DIM };

    f32x16 acc[2][2] = {};

    // stage chunk kt (all 4 tiles, 8 gload_lds per thread) into buffer buf.
    // Linear LDS dest; global source column pre-swizzled (rule #21).
    auto STAGE = [&](int kt, int buf) {
        int kc = kt * BK;
        #pragma unroll
        for (int t = 0; t < 4; ++t) {
            #pragma unroll
            for (int lg = 0; lg < 2; ++lg) {
                int ci0 = lg * 256 + wid * 64;    // wave-uniform 16B-chunk base
                int ci  = ci0 + lane;
                int r   = ci >> 2;                // tile row 0..127
                int sl  = ci & 3;                 // physical 16B slot 0..3
                int slin = sl ^ ((r >> 1) & 3);
                gload_lds16(srcs[t] + (size_t)r * D_DIM + kc + slin * 8,
                            &lds[buf][t][ci0 * 8]);
            }
        }
    };

    // depth-2 prologue: chunks 0 and 1 in flight (8 + 8 loads per thread)
    STAGE(0, 0);
    STAGE(1, 1);

    #pragma unroll 1
    for (int kt = 0; kt < NCHUNK; ++kt) {
        int buf = kt & 1;

        // wait: my 8 loads of chunk kt done; chunk kt+1's 8 stay in flight
        if (kt < NCHUNK - 1) asm volatile("s_waitcnt vmcnt(8)" ::: "memory");
        else                 asm volatile("s_waitcnt vmcnt(0)" ::: "memory");
        __builtin_amdgcn_s_barrier();     // raw barrier: no compiler vmcnt(0) drain

        #pragma unroll
        for (int kap = 0; kap < 2; ++kap) {            // two K=16 steps in BK=32
            int s = kap * 2 + khalf;                   // logical 16B slot
            s16x8 ah[2], al[2], bh[2], bl[2];
            #pragma unroll
            for (int mt = 0; mt < 2; ++mt) {
                int r  = wrow * 64 + mt * 32 + c32;
                int sp = s ^ ((r >> 1) & 3);           // T2 swizzled read
                ah[mt] = *(const s16x8*)&lds[buf][0][r * BK + sp * 8];
                al[mt] = *(const s16x8*)&lds[buf][1][r * BK + sp * 8];
            }
            #pragma unroll
            for (int nt = 0; nt < 2; ++nt) {
                int r  = wcol * 64 + nt * 32 + c32;
                int sp = s ^ ((r >> 1) & 3);
                bh[nt] = *(const s16x8*)&lds[buf][2][r * BK + sp * 8];
                bl[nt] = *(const s16x8*)&lds[buf][3][r * BK + sp * 8];
            }
            __builtin_amdgcn_s_setprio(1);             // T5
            #pragma unroll
            for (int mt = 0; mt < 2; ++mt)
                #pragma unroll
                for (int nt = 0; nt < 2; ++nt) {
                    acc[mt][nt] = __builtin_amdgcn_mfma_f32_32x32x16_bf16(ah[mt], bh[nt], acc[mt][nt], 0, 0, 0);
                    acc[mt][nt] = __builtin_amdgcn_mfma_f32_32x32x16_bf16(ah[mt], bl[nt], acc[mt][nt], 0, 0, 0);
                    acc[mt][nt] = __builtin_amdgcn_mfma_f32_32x32x16_bf16(al[mt], bh[nt], acc[mt][nt], 0, 0, 0);
                }
            __builtin_amdgcn_s_setprio(0);
        }

        // my ds_reads retired -> safe for others to overwrite after barrier
        asm volatile("s_waitcnt lgkmcnt(0)" ::: "memory");
        __builtin_amdgcn_s_barrier();

        if (kt + 2 < NCHUNK) STAGE(kt + 2, buf);   // refill freed buffer, no wait
    }

    // fused epilogue: d2 -> 5-kernel sum. C/D: col=lane&31, row=(reg&3)+8*(reg>>2)+4*khalf
    float nc = *negc;
    float sjn[2];
    #pragma unroll
    for (int nt = 0; nt < 2; ++nt)
        sjn[nt] = sq[rowB + wcol * 64 + nt * 32 + c32];
    float tsum = 0.f;
    #pragma unroll
    for (int mt = 0; mt < 2; ++mt) {
        #pragma unroll
        for (int reg = 0; reg < 16; ++reg) {
            int i = rowA + wrow * 64 + mt * 32 + (reg & 3) + 8 * (reg >> 2) + 4 * khalf;
            float si = sq[i];
            #pragma unroll
            for (int nt = 0; nt < 2; ++nt) {
                float d2 = fmaxf(si + sjn[nt] - 2.0f * acc[mt][nt][reg], 0.f);
                float u  = exp2f(nc * d2);
                float u2 = u * u, u4 = u2 * u2, u8 = u4 * u4;
                tsum += u + u2 + u4 + u8 + u8 * u8;
            }
        }
    }
    float scale = (((it < 32) == (jt < 32)) ? 1.f : -1.f) * ((it == jt) ? 1.f : 2.f);
    tsum *= scale;

    #pragma unroll
    for (int off = 32; off; off >>= 1) tsum += __shfl_down(tsum, off, 64);
    if (lane == 0) wsum[wid] = tsum;
    __syncthreads();
    if (tid == 0) {
        float t = wsum[0] + wsum[1] + wsum[2] + wsum[3];
        atomicAdd(accum, (double)t);
    }
}

__global__ void finalize_kernel(const double* __restrict__ accum, float* __restrict__ out) {
    out[0] = (float)(accum[0] / ((double)B_HALF * (double)B_HALF));
}

extern "C" void kernel_launch(void* const* d_in, const int* in_sizes, int n_in,
                              void* d_out, int out_size, void* d_ws, size_t ws_size,
                              hipStream_t stream) {
    const float* src = (const float*)d_in[0];
    const float* tgt = (const float*)d_in[1];
    float* out = (float*)d_out;

    char* ws = (char*)d_ws;
    float*  sq      = (float*)ws;                         // 32 KB
    float*  colpart = (float*)(ws + 32768);               // 64 KB (64 x 256)
    float*  negc    = (float*)(ws + 98304);
    double* accum   = (double*)(ws + 98312);
    ushort* hi      = (ushort*)(ws + 131072);             // 4 MB
    ushort* lo      = (ushort*)(ws + 131072 + (size_t)N_TOTAL * D_DIM * 2);  // 4 MB

    prep_kernel<<<N_TOTAL / 4, 256, 0, stream>>>(src, tgt, hi, lo, sq);
    colpart_kernel<<<64, 256, 0, stream>>>(src, tgt, colpart);
    bw_kernel<<<1, 256, 0, stream>>>(sq, colpart, negc, accum);
    mmd_mfma<<<NTRI, 256, 0, stream>>>(hi, lo, sq, negc, accum);
    finalize_kernel<<<1, 1, 0, stream>>>(accum, out);
}

// Round 8
// 112.797 us; speedup vs baseline: 1.0070x; 1.0070x over previous
//
#include <hip/hip_runtime.h>
#include <hip/hip_bf16.h>

// MMD loss via single-plane fp16 MFMA Gram pass.
//   fp16 has 11 mantissa bits: dot err ~8e-3 vs bandwidth ~128 -> final err ~1e-7.
//   d2 = sq_i + sq_j - 2 dot (sq exact f32);  kernels = u+u^2+u^4+u^8+u^16.
// 128^2 tile, 4 waves (2x2 of 64x64), mfma_f32_32x32x16_f16, BK=32,
// dbuf 32KB LDS -> 4 blocks/CU. Counted-vmcnt depth-2 pipeline, raw barriers.
// T2 swizzle sp=s^((r>>1)&3) both-sides, T1 XCD swizzle, T5 setprio.

#define N_TOTAL 8192
#define B_HALF 4096
#define D_DIM 256
#define TILE 128
#define NTILE 64          // 8192/128
#define NTRI 2080         // 64*65/2
#define BK 32
#define NCHUNK 8          // 256/32

typedef float f32x16 __attribute__((ext_vector_type(16)));
typedef _Float16 f16x8 __attribute__((ext_vector_type(8)));

__device__ __forceinline__ const float* row_base(const float* src, const float* tgt, int r) {
    return (r < B_HALF) ? src + (size_t)r * D_DIM : tgt + (size_t)(r - B_HALF) * D_DIM;
}

// fused: fp16 convert + row sq + per-block column partials. wave per row.
__global__ __launch_bounds__(256) void prep_kernel(const float* __restrict__ src,
                                                   const float* __restrict__ tgt,
                                                   _Float16* __restrict__ a16,
                                                   float* __restrict__ sq,
                                                   float* __restrict__ colpart) {
    __shared__ float cp[4][D_DIM];
    int w = threadIdx.x >> 6, lane = threadIdx.x & 63;
    int row = blockIdx.x * 4 + w;
    const float* rp = row_base(src, tgt, row);
    float4 v = ((const float4*)rp)[lane];
    float f[4] = {v.x, v.y, v.z, v.w};
    _Float16 h[4];
    #pragma unroll
    for (int e = 0; e < 4; ++e) {
        h[e] = (_Float16)f[e];
        cp[w][lane * 4 + e] = f[e];
    }
    ((ushort4*)(a16 + (size_t)row * D_DIM))[lane] = *(ushort4*)h;
    float s = f[0]*f[0] + f[1]*f[1] + f[2]*f[2] + f[3]*f[3];
    #pragma unroll
    for (int off = 32; off; off >>= 1) s += __shfl_down(s, off, 64);
    if (lane == 0) sq[row] = s;
    __syncthreads();
    int t = threadIdx.x;
    colpart[blockIdx.x * D_DIM + t] = cp[0][t] + cp[1][t] + cp[2][t] + cp[3][t];
}

__global__ __launch_bounds__(256) void bw_kernel(const float* __restrict__ sq,
                                                 const float* __restrict__ colpart,
                                                 float* __restrict__ negc,
                                                 double* __restrict__ accum) {
    __shared__ double red[256];
    int t = threadIdx.x;
    double s = 0.0;
    for (int i = t; i < N_TOTAL; i += 256) s += (double)sq[i];
    red[t] = s;
    __syncthreads();
    for (int off = 128; off; off >>= 1) {
        if (t < off) red[t] += red[t + off];
        __syncthreads();
    }
    double sumsq = red[0];
    __syncthreads();
    float c = 0.f;
    for (int k = 0; k < N_TOTAL / 4; ++k) c += colpart[k * D_DIM + t];
    red[t] = (double)c * (double)c;
    __syncthreads();
    for (int off = 128; off; off >>= 1) {
        if (t < off) red[t] += red[t + off];
        __syncthreads();
    }
    if (t == 0) {
        double S1 = 2.0 * (double)N_TOTAL * sumsq - 2.0 * red[0];
        double nn = (double)N_TOTAL * (double)N_TOTAL - (double)N_TOTAL;
        double bw = S1 / nn / 4.0;    // KERNEL_MUL^(KERNEL_NUM//2) = 4
        negc[0] = (float)(-1.4426950408889634 / (16.0 * bw));
        accum[0] = 0.0;
    }
}

__device__ __forceinline__ void gload_lds16(const void* g, void* l) {
    __builtin_amdgcn_global_load_lds((const __attribute__((address_space(1))) unsigned int*)g,
                                     (__attribute__((address_space(3))) unsigned int*)l,
                                     16, 0, 0);
}

__global__ __launch_bounds__(256, 4) void mmd_mfma(const _Float16* __restrict__ a16,
                                                   const float* __restrict__ sq,
                                                   const float* __restrict__ negc,
                                                   double* __restrict__ accum) {
    // [buf][tile: 0=A 1=B][128 rows x 32 k] fp16  = 32 KB total
    __shared__ _Float16 lds[2][2][TILE * BK];
    __shared__ float wsum[4];

    // T1: XCD swizzle (2080 % 8 == 0 -> bijective), then triangle decode
    int b  = blockIdx.x;
    int bs = (b & 7) * (NTRI / 8) + (b >> 3);
    int it = 0, cum = 0;
    while (cum + (NTILE - it) <= bs) { cum += NTILE - it; ++it; }
    int jt = it + (bs - cum);

    int tid = threadIdx.x, lane = tid & 63, wid = tid >> 6;
    int wrow = wid >> 1, wcol = wid & 1;      // 2x2 wave grid; per-wave 64x64
    int rowA = it * TILE, rowB = jt * TILE;
    int c32 = lane & 31, khalf = lane >> 5;

    const _Float16* srcs[2] = { a16 + (size_t)rowA * D_DIM,
                                a16 + (size_t)rowB * D_DIM };

    f32x16 acc[2][2] = {};

    // stage chunk kt (A+B tiles, 4 gload_lds per thread) into buffer buf.
    // Linear LDS dest; global source column pre-swizzled (rule #21).
    auto STAGE = [&](int kt, int buf) {
        int kc = kt * BK;
        #pragma unroll
        for (int t = 0; t < 2; ++t) {
            #pragma unroll
            for (int lg = 0; lg < 2; ++lg) {
                int ci0 = lg * 256 + wid * 64;    // wave-uniform 16B-chunk base
                int ci  = ci0 + lane;
                int r   = ci >> 2;                // tile row 0..127
                int sl  = ci & 3;                 // physical 16B slot 0..3
                int slin = sl ^ ((r >> 1) & 3);
                gload_lds16(srcs[t] + (size_t)r * D_DIM + kc + slin * 8,
                            &lds[buf][t][ci0 * 8]);
            }
        }
    };

    // depth-2 prologue: chunks 0 and 1 in flight (4 + 4 loads per thread)
    STAGE(0, 0);
    STAGE(1, 1);

    #pragma unroll 1
    for (int kt = 0; kt < NCHUNK; ++kt) {
        int buf = kt & 1;

        // wait: my 4 loads of chunk kt done; chunk kt+1's 4 stay in flight
        if (kt < NCHUNK - 1) asm volatile("s_waitcnt vmcnt(4)" ::: "memory");
        else                 asm volatile("s_waitcnt vmcnt(0)" ::: "memory");
        __builtin_amdgcn_s_barrier();     // raw barrier: no compiler vmcnt(0) drain

        #pragma unroll
        for (int kap = 0; kap < 2; ++kap) {            // two K=16 steps in BK=32
            int s = kap * 2 + khalf;                   // logical 16B slot
            f16x8 af[2], bf[2];
            #pragma unroll
            for (int mt = 0; mt < 2; ++mt) {
                int r  = wrow * 64 + mt * 32 + c32;
                int sp = s ^ ((r >> 1) & 3);           // T2 swizzled read
                af[mt] = *(const f16x8*)&lds[buf][0][r * BK + sp * 8];
            }
            #pragma unroll
            for (int nt = 0; nt < 2; ++nt) {
                int r  = wcol * 64 + nt * 32 + c32;
                int sp = s ^ ((r >> 1) & 3);
                bf[nt] = *(const f16x8*)&lds[buf][1][r * BK + sp * 8];
            }
            __builtin_amdgcn_s_setprio(1);             // T5
            #pragma unroll
            for (int mt = 0; mt < 2; ++mt)
                #pragma unroll
                for (int nt = 0; nt < 2; ++nt)
                    acc[mt][nt] = __builtin_amdgcn_mfma_f32_32x32x16_f16(af[mt], bf[nt], acc[mt][nt], 0, 0, 0);
            __builtin_amdgcn_s_setprio(0);
        }

        // my ds_reads retired -> safe for others to overwrite after barrier
        asm volatile("s_waitcnt lgkmcnt(0)" ::: "memory");
        __builtin_amdgcn_s_barrier();

        if (kt + 2 < NCHUNK) STAGE(kt + 2, buf);   // refill freed buffer, no wait
    }

    // fused epilogue: d2 -> 5-kernel sum. C/D: col=lane&31, row=(reg&3)+8*(reg>>2)+4*khalf
    float nc = *negc;
    float sjn[2];
    #pragma unroll
    for (int nt = 0; nt < 2; ++nt)
        sjn[nt] = sq[rowB + wcol * 64 + nt * 32 + c32];
    float tsum = 0.f;
    #pragma unroll
    for (int mt = 0; mt < 2; ++mt) {
        #pragma unroll
        for (int reg = 0; reg < 16; ++reg) {
            int i = rowA + wrow * 64 + mt * 32 + (reg & 3) + 8 * (reg >> 2) + 4 * khalf;
            float si = sq[i];
            #pragma unroll
            for (int nt = 0; nt < 2; ++nt) {
                float d2 = fmaxf(si + sjn[nt] - 2.0f * acc[mt][nt][reg], 0.f);
                float u  = exp2f(nc * d2);
                float u2 = u * u, u4 = u2 * u2, u8 = u4 * u4;
                tsum += u + u2 + u4 + u8 + u8 * u8;
            }
        }
    }
    float scale = (((it < 32) == (jt < 32)) ? 1.f : -1.f) * ((it == jt) ? 1.f : 2.f);
    tsum *= scale;

    #pragma unroll
    for (int off = 32; off; off >>= 1) tsum += __shfl_down(tsum, off, 64);
    if (lane == 0) wsum[wid] = tsum;
    __syncthreads();
    if (tid == 0) {
        float t = wsum[0] + wsum[1] + wsum[2] + wsum[3];
        atomicAdd(accum, (double)t);
    }
}

__global__ void finalize_kernel(const double* __restrict__ accum, float* __restrict__ out) {
    out[0] = (float)(accum[0] / ((double)B_HALF * (double)B_HALF));
}

extern "C" void kernel_launch(void* const* d_in, const int* in_sizes, int n_in,
                              void* d_out, int out_size, void* d_ws, size_t ws_size,
                              hipStream_t stream) {
    const float* src = (const float*)d_in[0];
    const float* tgt = (const float*)d_in[1];
    float* out = (float*)d_out;

    char* ws = (char*)d_ws;
    float*  sq      = (float*)ws;                         // 32 KB
    float*  colpart = (float*)(ws + 32768);               // 2048 x 256 f32 = 2 MB
    float*  negc    = (float*)(ws + 32768 + 2097152);
    double* accum   = (double*)(ws + 32768 + 2097152 + 8);
    _Float16* a16   = (_Float16*)(ws + 4194304);          // 4 MB plane

    prep_kernel<<<N_TOTAL / 4, 256, 0, stream>>>(src, tgt, a16, sq, colpart);
    bw_kernel<<<1, 256, 0, stream>>>(sq, colpart, negc, accum);
    mmd_mfma<<<NTRI, 256, 0, stream>>>(a16, sq, negc, accum);
    finalize_kernel<<<1, 1, 0, stream>>>(accum, out);
}

// Round 9
// 74.032 us; speedup vs baseline: 1.5343x; 1.5236x over previous
//
#include <hip/hip_runtime.h>
#include <hip/hip_bf16.h>

// MMD loss via single-plane fp16 MFMA Gram pass.
//   fp16: dot err ~8e-3 vs bandwidth ~128 -> final err ~1e-7 (absmax 0.0 measured).
//   d2 = sq_i + sq_j - 2 dot (sq exact f32);  kernels = u+u^2+u^4+u^8+u^16.
// 128^2 tile, 4 waves (2x2 of 64x64), mfma_f32_32x32x16_f16, BK=32,
// dbuf 32KB LDS. Counted-vmcnt depth-2 pipeline, raw barriers.
// T2 swizzle sp=s^((r>>1)&3) both-sides, T1 XCD swizzle, T5 setprio.
// Column-sum: separate 64-block partial kernel (round-5 structure; the
// 2048-partial prep fusion made single-block bw 60us -> reverted).

#define N_TOTAL 8192
#define B_HALF 4096
#define D_DIM 256
#define TILE 128
#define NTILE 64          // 8192/128
#define NTRI 2080         // 64*65/2
#define BK 32
#define NCHUNK 8          // 256/32

typedef float f32x16 __attribute__((ext_vector_type(16)));
typedef _Float16 f16x8 __attribute__((ext_vector_type(8)));

__device__ __forceinline__ const float* row_base(const float* src, const float* tgt, int r) {
    return (r < B_HALF) ? src + (size_t)r * D_DIM : tgt + (size_t)(r - B_HALF) * D_DIM;
}

// fp16 convert + row sq. one wave per row, 4 rows/block.
__global__ __launch_bounds__(256) void prep_kernel(const float* __restrict__ src,
                                                   const float* __restrict__ tgt,
                                                   _Float16* __restrict__ a16,
                                                   float* __restrict__ sq) {
    int w = threadIdx.x >> 6, lane = threadIdx.x & 63;
    int row = blockIdx.x * 4 + w;
    const float* rp = row_base(src, tgt, row);
    float4 v = ((const float4*)rp)[lane];
    float f[4] = {v.x, v.y, v.z, v.w};
    _Float16 h[4];
    #pragma unroll
    for (int e = 0; e < 4; ++e) h[e] = (_Float16)f[e];
    ((ushort4*)(a16 + (size_t)row * D_DIM))[lane] = *(ushort4*)h;
    float s = f[0]*f[0] + f[1]*f[1] + f[2]*f[2] + f[3]*f[3];
    #pragma unroll
    for (int off = 32; off; off >>= 1) s += __shfl_down(s, off, 64);
    if (lane == 0) sq[row] = s;
}

// per-block partial column sums (64 blocks x 128 rows, no atomics)
__global__ __launch_bounds__(256) void colpart_kernel(const float* __restrict__ src,
                                                      const float* __restrict__ tgt,
                                                      float* __restrict__ colpart) {
    int t  = threadIdx.x;
    int r0 = blockIdx.x * 128;
    float s = 0.f;
    for (int r = r0; r < r0 + 128; ++r)
        s += row_base(src, tgt, r)[t];
    colpart[blockIdx.x * D_DIM + t] = s;
}

__global__ __launch_bounds__(256) void bw_kernel(const float* __restrict__ sq,
                                                 const float* __restrict__ colpart,
                                                 float* __restrict__ negc,
                                                 double* __restrict__ accum) {
    __shared__ double red[256];
    int t = threadIdx.x;
    double s = 0.0;
    for (int i = t; i < N_TOTAL; i += 256) s += (double)sq[i];
    red[t] = s;
    __syncthreads();
    for (int off = 128; off; off >>= 1) {
        if (t < off) red[t] += red[t + off];
        __syncthreads();
    }
    double sumsq = red[0];
    __syncthreads();
    float c = 0.f;
    #pragma unroll
    for (int k = 0; k < 64; ++k) c += colpart[k * D_DIM + t];
    red[t] = (double)c * (double)c;
    __syncthreads();
    for (int off = 128; off; off >>= 1) {
        if (t < off) red[t] += red[t + off];
        __syncthreads();
    }
    if (t == 0) {
        double S1 = 2.0 * (double)N_TOTAL * sumsq - 2.0 * red[0];
        double nn = (double)N_TOTAL * (double)N_TOTAL - (double)N_TOTAL;
        double bw = S1 / nn / 4.0;    // KERNEL_MUL^(KERNEL_NUM//2) = 4
        negc[0] = (float)(-1.4426950408889634 / (16.0 * bw));
        accum[0] = 0.0;
    }
}

__device__ __forceinline__ void gload_lds16(const void* g, void* l) {
    __builtin_amdgcn_global_load_lds((const __attribute__((address_space(1))) unsigned int*)g,
                                     (__attribute__((address_space(3))) unsigned int*)l,
                                     16, 0, 0);
}

__global__ __launch_bounds__(256, 4) void mmd_mfma(const _Float16* __restrict__ a16,
                                                   const float* __restrict__ sq,
                                                   const float* __restrict__ negc,
                                                   double* __restrict__ accum) {
    // [buf][tile: 0=A 1=B][128 rows x 32 k] fp16  = 32 KB total
    __shared__ _Float16 lds[2][2][TILE * BK];
    __shared__ float wsum[4];

    // T1: XCD swizzle (2080 % 8 == 0 -> bijective), then triangle decode
    int b  = blockIdx.x;
    int bs = (b & 7) * (NTRI / 8) + (b >> 3);
    int it = 0, cum = 0;
    while (cum + (NTILE - it) <= bs) { cum += NTILE - it; ++it; }
    int jt = it + (bs - cum);

    int tid = threadIdx.x, lane = tid & 63, wid = tid >> 6;
    int wrow = wid >> 1, wcol = wid & 1;      // 2x2 wave grid; per-wave 64x64
    int rowA = it * TILE, rowB = jt * TILE;
    int c32 = lane & 31, khalf = lane >> 5;

    const _Float16* srcs[2] = { a16 + (size_t)rowA * D_DIM,
                                a16 + (size_t)rowB * D_DIM };

    f32x16 acc[2][2] = {};

    // stage chunk kt (A+B tiles, 4 gload_lds per thread) into buffer buf.
    // Linear LDS dest; global source column pre-swizzled (rule #21).
    auto STAGE = [&](int kt, int buf) {
        int kc = kt * BK;
        #pragma unroll
        for (int t = 0; t < 2; ++t) {
            #pragma unroll
            for (int lg = 0; lg < 2; ++lg) {
                int ci0 = lg * 256 + wid * 64;    // wave-uniform 16B-chunk base
                int ci  = ci0 + lane;
                int r   = ci >> 2;                // tile row 0..127
                int sl  = ci & 3;                 // physical 16B slot 0..3
                int slin = sl ^ ((r >> 1) & 3);
                gload_lds16(srcs[t] + (size_t)r * D_DIM + kc + slin * 8,
                            &lds[buf][t][ci0 * 8]);
            }
        }
    };

    // depth-2 prologue: chunks 0 and 1 in flight (4 + 4 loads per thread)
    STAGE(0, 0);
    STAGE(1, 1);

    #pragma unroll 1
    for (int kt = 0; kt < NCHUNK; ++kt) {
        int buf = kt & 1;

        // wait: my 4 loads of chunk kt done; chunk kt+1's 4 stay in flight
        if (kt < NCHUNK - 1) asm volatile("s_waitcnt vmcnt(4)" ::: "memory");
        else                 asm volatile("s_waitcnt vmcnt(0)" ::: "memory");
        __builtin_amdgcn_s_barrier();     // raw barrier: no compiler vmcnt(0) drain

        #pragma unroll
        for (int kap = 0; kap < 2; ++kap) {            // two K=16 steps in BK=32
            int s = kap * 2 + khalf;                   // logical 16B slot
            f16x8 af[2], bf[2];
            #pragma unroll
            for (int mt = 0; mt < 2; ++mt) {
                int r  = wrow * 64 + mt * 32 + c32;
                int sp = s ^ ((r >> 1) & 3);           // T2 swizzled read
                af[mt] = *(const f16x8*)&lds[buf][0][r * BK + sp * 8];
            }
            #pragma unroll
            for (int nt = 0; nt < 2; ++nt) {
                int r  = wcol * 64 + nt * 32 + c32;
                int sp = s ^ ((r >> 1) & 3);
                bf[nt] = *(const f16x8*)&lds[buf][1][r * BK + sp * 8];
            }
            __builtin_amdgcn_s_setprio(1);             // T5
            #pragma unroll
            for (int mt = 0; mt < 2; ++mt)
                #pragma unroll
                for (int nt = 0; nt < 2; ++nt)
                    acc[mt][nt] = __builtin_amdgcn_mfma_f32_32x32x16_f16(af[mt], bf[nt], acc[mt][nt], 0, 0, 0);
            __builtin_amdgcn_s_setprio(0);
        }

        // my ds_reads retired -> safe for others to overwrite after barrier
        asm volatile("s_waitcnt lgkmcnt(0)" ::: "memory");
        __builtin_amdgcn_s_barrier();

        if (kt + 2 < NCHUNK) STAGE(kt + 2, buf);   // refill freed buffer, no wait
    }

    // fused epilogue: d2 -> 5-kernel sum. C/D: col=lane&31, row=(reg&3)+8*(reg>>2)+4*khalf
    float nc = *negc;
    float sjn[2];
    #pragma unroll
    for (int nt = 0; nt < 2; ++nt)
        sjn[nt] = sq[rowB + wcol * 64 + nt * 32 + c32];
    float tsum = 0.f;
    #pragma unroll
    for (int mt = 0; mt < 2; ++mt) {
        #pragma unroll
        for (int reg = 0; reg < 16; ++reg) {
            int i = rowA + wrow * 64 + mt * 32 + (reg & 3) + 8 * (reg >> 2) + 4 * khalf;
            float si = sq[i];
            #pragma unroll
            for (int nt = 0; nt < 2; ++nt) {
                float d2 = fmaxf(si + sjn[nt] - 2.0f * acc[mt][nt][reg], 0.f);
                float u  = exp2f(nc * d2);
                float u2 = u * u, u4 = u2 * u2, u8 = u4 * u4;
                tsum += u + u2 + u4 + u8 + u8 * u8;
            }
        }
    }
    float scale = (((it < 32) == (jt < 32)) ? 1.f : -1.f) * ((it == jt) ? 1.f : 2.f);
    tsum *= scale;

    #pragma unroll
    for (int off = 32; off; off >>= 1) tsum += __shfl_down(tsum, off, 64);
    if (lane == 0) wsum[wid] = tsum;
    __syncthreads();
    if (tid == 0) {
        float t = wsum[0] + wsum[1] + wsum[2] + wsum[3];
        atomicAdd(accum, (double)t);
    }
}

__global__ void finalize_kernel(const double* __restrict__ accum, float* __restrict__ out) {
    out[0] = (float)(accum[0] / ((double)B_HALF * (double)B_HALF));
}

extern "C" void kernel_launch(void* const* d_in, const int* in_sizes, int n_in,
                              void* d_out, int out_size, void* d_ws, size_t ws_size,
                              hipStream_t stream) {
    const float* src = (const float*)d_in[0];
    const float* tgt = (const float*)d_in[1];
    float* out = (float*)d_out;

    char* ws = (char*)d_ws;
    float*  sq      = (float*)ws;                         // 32 KB
    float*  colpart = (float*)(ws + 32768);               // 64 x 256 f32 = 64 KB
    float*  negc    = (float*)(ws + 98304);
    double* accum   = (double*)(ws + 98312);
    _Float16* a16   = (_Float16*)(ws + 131072);           // 4 MB plane

    prep_kernel<<<N_TOTAL / 4, 256, 0, stream>>>(src, tgt, a16, sq);
    colpart_kernel<<<64, 256, 0, stream>>>(src, tgt, colpart);
    bw_kernel<<<1, 256, 0, stream>>>(sq, colpart, negc, accum);
    mmd_mfma<<<NTRI, 256, 0, stream>>>(a16, sq, negc, accum);
    finalize_kernel<<<1, 1, 0, stream>>>(accum, out);
}